// Round 1
// baseline (1671.071 us; speedup 1.0000x reference)
//
#include <hip/hip_runtime.h>
#include <math.h>

#define BETA_F 0.9f
#define THR1_F 1.0f
#define THR2_F 0.8f

// ---------------- init: delay factors + state zeroing ----------------
__global__ void k_init(const float* __restrict__ cd1, const float* __restrict__ v1,
                       const float* __restrict__ cd2, const float* __restrict__ v2,
                       float* __restrict__ df1, float* __restrict__ df2,
                       float* __restrict__ p1, float* __restrict__ p2,
                       float* __restrict__ acc2,
                       int I, int H, int BI, int BH) {
    float vc1 = fminf(fmaxf(v1[0], 0.0f), 0.999f);
    float vc2 = fminf(fmaxf(v2[0], 0.0f), 0.999f);
    double g1 = 1.0 / sqrt(1.0 - (double)vc1 * (double)vc1);
    double g2 = 1.0 / sqrt(1.0 - (double)vc2 * (double)vc2);
    int total = I + H + BI + BH + BH;
    for (int idx = blockIdx.x * blockDim.x + threadIdx.x; idx < total;
         idx += gridDim.x * blockDim.x) {
        if (idx < I) {
            df1[idx] = (float)exp(-(g1 * fabs((double)cd1[idx]) * (double)vc1));
        } else if (idx < I + H) {
            int j = idx - I;
            df2[j] = (float)exp(-(g2 * fabs((double)cd2[j]) * (double)vc2));
        } else if (idx < I + H + BI) {
            p1[idx - I - H] = 0.0f;
        } else if (idx < I + H + BI + BH) {
            p2[idx - I - H - BI] = 0.0f;
        } else {
            acc2[idx - I - H - BI - BH] = 0.0f;
        }
    }
}

// ---------------- time-weight table (normalized) ----------------
__global__ void k_tw(const float* __restrict__ v1, float* __restrict__ tw, int T) {
    __shared__ float sh[256];
    float vc = fminf(fmaxf(v1[0], 0.0f), 0.999f);
    double g = 1.0 / sqrt(1.0 - (double)vc * (double)vc);
    int t = threadIdx.x;
    float val = 0.0f;
    if (t < T) val = (float)exp(-(g - 1.0) * (double)t);
    sh[t] = val;
    __syncthreads();
    for (int s = 128; s > 0; s >>= 1) {
        if (t < s) sh[t] += sh[t + s];
        __syncthreads();
    }
    float sum = sh[0];
    if (t < T) tw[t] = val / sum;
}

// ---------------- layer-1 LIF over a chunk of timesteps ----------------
__global__ void k_lif1(const float* __restrict__ x, const float* __restrict__ df1,
                       float* __restrict__ p1, float* __restrict__ s1,
                       int Bsz, int T, int I, int t0, int TC) {
    int idx = blockIdx.x * blockDim.x + threadIdx.x;  // b*I + i
    if (idx >= Bsz * I) return;
    int b = idx / I;
    int i = idx - b * I;
    float df = df1[i];
    float p = p1[idx];
    const float* xp = x + ((size_t)b * T + t0) * I + i;
    size_t strideS = (size_t)Bsz * I;
    for (int t = 0; t < TC; ++t) {
        float xv = xp[(size_t)t * I];
        // match numpy: pot*BETA + inp*df, each op rounded separately (no fma)
        float pn = __fadd_rn(__fmul_rn(p, BETA_F), __fmul_rn(xv, df));
        bool spk = pn > THR1_F;
        s1[(size_t)t * strideS + idx] = spk ? 1.0f : 0.0f;
        p = spk ? 0.0f : pn;
    }
    p1[idx] = p;
}

// ---------------- layer-2 LIF + weighted spike accumulation ----------------
__global__ void k_lif2(const float* __restrict__ h, const float* __restrict__ df2,
                       const float* __restrict__ tw, float* __restrict__ p2,
                       float* __restrict__ acc2, int Bsz, int H, int t0, int TC) {
    int idx = blockIdx.x * blockDim.x + threadIdx.x;  // b*H + j
    if (idx >= Bsz * H) return;
    int j = idx % H;
    float df = df2[j];
    float p = p2[idx];
    float acc = acc2[idx];
    size_t strideH = (size_t)Bsz * H;
    for (int t = 0; t < TC; ++t) {
        float hv = h[(size_t)t * strideH + idx];
        float pn = __fadd_rn(__fmul_rn(p, BETA_F), __fmul_rn(hv, df));
        bool spk = pn > THR2_F;
        if (spk) acc += tw[t0 + t];
        p = spk ? 0.0f : pn;
    }
    p2[idx] = p;
    acc2[idx] = acc;
}

// ---------------- f32 GEMM: C = A (MxK) * B^T (NxK) + bias, opt scale/bias2 ----
#define GT 128
#define GK 16

__global__ __launch_bounds__(256)
void k_gemm_nt(const float* __restrict__ A, const float* __restrict__ Bm,
               const float* __restrict__ bias, const float* __restrict__ scale,
               const float* __restrict__ bias2, float* __restrict__ C,
               int M, int N, int K) {
    __shared__ float As[GK][GT + 4];  // +4 keeps 16B row alignment, kills write conflicts
    __shared__ float Bs[GK][GT + 4];
    int tid = threadIdx.x;
    int mBase = blockIdx.y * GT;
    int nBase = blockIdx.x * GT;
    int lr = tid >> 2;         // 0..63 row within half-tile
    int lk = (tid & 3) * 4;    // 0,4,8,12 k offset
    const float* Aptr = A + (size_t)(mBase + lr) * K + lk;
    const float* Bptr = Bm + (size_t)(nBase + lr) * K + lk;
    int ty = tid >> 4, tx = tid & 15;
    float acc[8][8];
#pragma unroll
    for (int i = 0; i < 8; i++)
#pragma unroll
        for (int j = 0; j < 8; j++) acc[i][j] = 0.0f;

    for (int k0 = 0; k0 < K; k0 += GK) {
#pragma unroll
        for (int p = 0; p < 2; p++) {
            float4 av = *(const float4*)(Aptr + (size_t)(p * 64) * K + k0);
            float4 bv = *(const float4*)(Bptr + (size_t)(p * 64) * K + k0);
            int row = lr + p * 64;
            As[lk + 0][row] = av.x; As[lk + 1][row] = av.y;
            As[lk + 2][row] = av.z; As[lk + 3][row] = av.w;
            Bs[lk + 0][row] = bv.x; Bs[lk + 1][row] = bv.y;
            Bs[lk + 2][row] = bv.z; Bs[lk + 3][row] = bv.w;
        }
        __syncthreads();
#pragma unroll
        for (int kk = 0; kk < GK; ++kk) {
            float4 a0 = *(const float4*)&As[kk][ty * 8];
            float4 a1 = *(const float4*)&As[kk][ty * 8 + 4];
            float4 b0 = *(const float4*)&Bs[kk][tx * 8];
            float4 b1 = *(const float4*)&Bs[kk][tx * 8 + 4];
            float a[8] = {a0.x, a0.y, a0.z, a0.w, a1.x, a1.y, a1.z, a1.w};
            float b[8] = {b0.x, b0.y, b0.z, b0.w, b1.x, b1.y, b1.z, b1.w};
#pragma unroll
            for (int i = 0; i < 8; i++)
#pragma unroll
                for (int j = 0; j < 8; j++)
                    acc[i][j] = fmaf(a[i], b[j], acc[i][j]);
        }
        __syncthreads();
    }
#pragma unroll
    for (int i = 0; i < 8; i++) {
        int row = mBase + ty * 8 + i;
#pragma unroll
        for (int j = 0; j < 8; j++) {
            int col = nBase + tx * 8 + j;
            float v = acc[i][j];
            if (bias) v += bias[col];
            if (scale) v = v * scale[col] + bias2[col];
            C[(size_t)row * N + col] = v;
        }
    }
}

extern "C" void kernel_launch(void* const* d_in, const int* in_sizes, int n_in,
                              void* d_out, int out_size, void* d_ws, size_t ws_size,
                              hipStream_t stream) {
    const float* x = (const float*)d_in[0];
    const float* cd1 = (const float*)d_in[1];
    const float* v1 = (const float*)d_in[2];
    const float* cd2 = (const float*)d_in[3];
    const float* v2 = (const float*)d_in[4];
    const float* W1 = (const float*)d_in[5];
    const float* b1 = (const float*)d_in[6];
    const float* W2 = (const float*)d_in[7];
    const float* b2 = (const float*)d_in[8];
    const float* out_scale = (const float*)d_in[9];
    const float* out_bias = (const float*)d_in[10];

    int I = in_sizes[1];
    int H = in_sizes[3];
    int O = in_sizes[8];
    int Bsz = out_size / O;
    int T = in_sizes[0] / (Bsz * I);

    // workspace layout (floats), 64-float aligned chunks
    float* ws = (float*)d_ws;
    size_t off = 0;
    auto alloc = [&](size_t n) {
        size_t cur = off;
        off += (n + 63) & ~(size_t)63;
        return cur;
    };
    size_t o_df1 = alloc(I);
    size_t o_df2 = alloc(H);
    size_t o_tw = alloc(T);
    size_t o_p1 = alloc((size_t)Bsz * I);
    size_t o_p2 = alloc((size_t)Bsz * H);
    size_t o_acc2 = alloc((size_t)Bsz * H);
    size_t persist = off;

    size_t wsFloats = ws_size / 4;
    size_t perStep = (size_t)Bsz * (I + H) + 128;
    int TC = 1;
    if (wsFloats > persist) {
        size_t tcMax = (wsFloats - persist) / perStep;
        TC = (int)(tcMax < (size_t)T ? tcMax : (size_t)T);
        if (TC < 1) TC = 1;
    }
    size_t o_s1 = alloc((size_t)TC * Bsz * I);
    size_t o_h = alloc((size_t)TC * Bsz * H);

    float* df1 = ws + o_df1;
    float* df2 = ws + o_df2;
    float* tw = ws + o_tw;
    float* p1 = ws + o_p1;
    float* p2 = ws + o_p2;
    float* acc2 = ws + o_acc2;
    float* s1c = ws + o_s1;
    float* hbuf = ws + o_h;

    k_init<<<2048, 256, 0, stream>>>(cd1, v1, cd2, v2, df1, df2, p1, p2, acc2, I, H,
                                     Bsz * I, Bsz * H);
    k_tw<<<1, 256, 0, stream>>>(v1, tw, T);

    for (int t0 = 0; t0 < T; t0 += TC) {
        int tc = (T - t0 < TC) ? (T - t0) : TC;
        k_lif1<<<(Bsz * I + 255) / 256, 256, 0, stream>>>(x, df1, p1, s1c, Bsz, T, I,
                                                          t0, tc);
        int Mrows = tc * Bsz;
        dim3 g1(H / GT, Mrows / GT);
        k_gemm_nt<<<g1, 256, 0, stream>>>(s1c, W1, b1, nullptr, nullptr, hbuf, Mrows,
                                          H, I);
        k_lif2<<<(Bsz * H + 255) / 256, 256, 0, stream>>>(hbuf, df2, tw, p2, acc2,
                                                          Bsz, H, t0, tc);
    }
    dim3 g2(O / GT, Bsz / GT);
    k_gemm_nt<<<g2, 256, 0, stream>>>(acc2, W2, b2, out_scale, out_bias,
                                      (float*)d_out, Bsz, O, H);
}

// Round 2
// 555.143 us; speedup vs baseline: 3.0102x; 3.0102x over previous
//
#include <hip/hip_runtime.h>
#include <hip/hip_bf16.h>
#include <math.h>

#define BETA_F 0.9f
#define THR1_F 1.0f
#define THR2_F 0.8f

typedef __attribute__((ext_vector_type(8))) short bf16x8;
typedef __attribute__((ext_vector_type(4))) float f32x4;

__device__ __forceinline__ void gload_lds16(const void* g, void* l) {
    __builtin_amdgcn_global_load_lds(
        (const __attribute__((address_space(1))) void*)g,
        (__attribute__((address_space(3))) void*)l, 16, 0, 0);
}

__device__ __forceinline__ ushort f2bf(float f) {
    __hip_bfloat16 h = __float2bfloat16(f);
    return *(ushort*)&h;
}
__device__ __forceinline__ float bf2f(ushort u) {
    __hip_bfloat16 h;
    *(ushort*)&h = u;
    return __bfloat162float(h);
}

// ---------------- init: delay factors + state zeroing ----------------
__global__ void k_init(const float* __restrict__ cd1, const float* __restrict__ v1,
                       const float* __restrict__ cd2, const float* __restrict__ v2,
                       float* __restrict__ df1, float* __restrict__ df2,
                       float* __restrict__ p1, float* __restrict__ p2,
                       float* __restrict__ acc2,
                       int I, int H, int BI, int BH) {
    float vc1 = fminf(fmaxf(v1[0], 0.0f), 0.999f);
    float vc2 = fminf(fmaxf(v2[0], 0.0f), 0.999f);
    double g1 = 1.0 / sqrt(1.0 - (double)vc1 * (double)vc1);
    double g2 = 1.0 / sqrt(1.0 - (double)vc2 * (double)vc2);
    int total = I + H + BI + BH + BH;
    for (int idx = blockIdx.x * blockDim.x + threadIdx.x; idx < total;
         idx += gridDim.x * blockDim.x) {
        if (idx < I) {
            df1[idx] = (float)exp(-(g1 * fabs((double)cd1[idx]) * (double)vc1));
        } else if (idx < I + H) {
            int j = idx - I;
            df2[j] = (float)exp(-(g2 * fabs((double)cd2[j]) * (double)vc2));
        } else if (idx < I + H + BI) {
            p1[idx - I - H] = 0.0f;
        } else if (idx < I + H + BI + BH) {
            p2[idx - I - H - BI] = 0.0f;
        } else {
            acc2[idx - I - H - BI - BH] = 0.0f;
        }
    }
}

// ---------------- time-weight table (normalized) ----------------
__global__ void k_tw(const float* __restrict__ v1, float* __restrict__ tw, int T) {
    __shared__ float sh[256];
    float vc = fminf(fmaxf(v1[0], 0.0f), 0.999f);
    double g = 1.0 / sqrt(1.0 - (double)vc * (double)vc);
    int t = threadIdx.x;
    float val = 0.0f;
    if (t < T) val = (float)exp(-(g - 1.0) * (double)t);
    sh[t] = val;
    __syncthreads();
    for (int s = 128; s > 0; s >>= 1) {
        if (t < s) sh[t] += sh[t + s];
        __syncthreads();
    }
    float sum = sh[0];
    if (t < T) tw[t] = val / sum;
}

// ---------------- split W1 into hi/lo bf16 ----------------
__global__ void k_wsplit(const float* __restrict__ W, ushort* __restrict__ hi,
                         ushort* __restrict__ lo, int n) {
    int i = blockIdx.x * blockDim.x + threadIdx.x;
    if (i >= n) return;
    float w = W[i];
    ushort h = f2bf(w);
    float hf = bf2f(h);
    ushort l = f2bf(w - hf);
    hi[i] = h;
    lo[i] = l;
}

// ---------------- layer-1 LIF over a chunk of timesteps (bf16 spikes) -------
__global__ void k_lif1(const float* __restrict__ x, const float* __restrict__ df1,
                       float* __restrict__ p1, ushort* __restrict__ s1,
                       int Bsz, int T, int I, int t0, int TC) {
    int idx = blockIdx.x * blockDim.x + threadIdx.x;  // b*I + i
    if (idx >= Bsz * I) return;
    int b = idx / I;
    int i = idx - b * I;
    float df = df1[i];
    float p = p1[idx];
    const float* xp = x + ((size_t)b * T + t0) * I + i;
    size_t strideS = (size_t)Bsz * I;
    for (int t = 0; t < TC; ++t) {
        float xv = xp[(size_t)t * I];
        float pn = __fadd_rn(__fmul_rn(p, BETA_F), __fmul_rn(xv, df));
        bool spk = pn > THR1_F;
        s1[(size_t)t * strideS + idx] = spk ? (ushort)0x3F80 : (ushort)0;
        p = spk ? 0.0f : pn;
    }
    p1[idx] = p;
}

// ---------------- layer-2 LIF + weighted spike accumulation ----------------
__global__ void k_lif2(const float* __restrict__ h, const float* __restrict__ df2,
                       const float* __restrict__ tw, float* __restrict__ p2,
                       float* __restrict__ acc2, int Bsz, int H, int t0, int TC) {
    int idx = blockIdx.x * blockDim.x + threadIdx.x;  // b*H + j
    if (idx >= Bsz * H) return;
    int j = idx % H;
    float df = df2[j];
    float p = p2[idx];
    float acc = acc2[idx];
    size_t strideH = (size_t)Bsz * H;
    for (int t = 0; t < TC; ++t) {
        float hv = h[(size_t)t * strideH + idx];
        float pn = __fadd_rn(__fmul_rn(p, BETA_F), __fmul_rn(hv, df));
        bool spk = pn > THR2_F;
        if (spk) acc += tw[t0 + t];
        p = spk ? 0.0f : pn;
    }
    p2[idx] = p;
    acc2[idx] = acc;
}

// ---------------- MFMA GEMM: C = A(bf16 spikes) @ (Whi+Wlo)^T + bias --------
// A: [M][K] bf16, Bhi/Blo: [N][K] bf16, C: [M][N] f32.  M%128==0, N%128==0, K%32==0.
__global__ __launch_bounds__(256)
void k_gemm_mfma(const ushort* __restrict__ A, const ushort* __restrict__ Bhi,
                 const ushort* __restrict__ Blo, const float* __restrict__ bias,
                 float* __restrict__ C, int N, int K, int gx) {
    __shared__ ushort As[128 * 32];
    __shared__ ushort Bh[128 * 32];
    __shared__ ushort Bl[128 * 32];
    int nwg = gridDim.x;
    int lin = blockIdx.x;
    int cpx = nwg >> 3;                    // nwg % 8 == 0 by construction
    int swz = (lin & 7) * cpx + (lin >> 3);
    int bx = swz % gx, by = swz / gx;
    int mBase = by * 128, nBase = bx * 128;
    int tid = threadIdx.x;
    int wid = tid >> 6, lane = tid & 63;

    // staging: 2 issues of 16B per matrix per thread; linear LDS, linear source
    int srow = tid >> 2;                   // 0..63
    int scol = (tid & 3) * 8;              // 0,8,16,24
    const ushort* aS0 = A + (size_t)(mBase + srow) * K + scol;
    const ushort* aS1 = A + (size_t)(mBase + 64 + srow) * K + scol;
    const ushort* bhS0 = Bhi + (size_t)(nBase + srow) * K + scol;
    const ushort* bhS1 = Bhi + (size_t)(nBase + 64 + srow) * K + scol;
    const ushort* blS0 = Blo + (size_t)(nBase + srow) * K + scol;
    const ushort* blS1 = Blo + (size_t)(nBase + 64 + srow) * K + scol;
    ushort* aD0 = As + wid * 512;          // wave-uniform LDS base + lane*16B
    ushort* aD1 = As + 2048 + wid * 512;
    ushort* bhD0 = Bh + wid * 512;
    ushort* bhD1 = Bh + 2048 + wid * 512;
    ushort* blD0 = Bl + wid * 512;
    ushort* blD1 = Bl + 2048 + wid * 512;

    int wr = wid >> 1, wc = wid & 1;       // wave's 64x64 quadrant
    int aoff = (wr * 64 + (lane & 15)) * 32 + (lane >> 4) * 8;
    int boff = (wc * 64 + (lane & 15)) * 32 + (lane >> 4) * 8;

    f32x4 acc[4][4];
#pragma unroll
    for (int i = 0; i < 4; i++)
#pragma unroll
        for (int j = 0; j < 4; j++) acc[i][j] = (f32x4)(0.0f);

    for (int k0 = 0; k0 < K; k0 += 32) {
        __syncthreads();
        gload_lds16(aS0 + k0, aD0);
        gload_lds16(aS1 + k0, aD1);
        gload_lds16(bhS0 + k0, bhD0);
        gload_lds16(bhS1 + k0, bhD1);
        gload_lds16(blS0 + k0, blD0);
        gload_lds16(blS1 + k0, blD1);
        __syncthreads();                   // compiler inserts vmcnt(0) drain
        bf16x8 af[4], bhf[4], blf[4];
#pragma unroll
        for (int f = 0; f < 4; f++) {
            af[f] = *(const bf16x8*)&As[aoff + f * 16 * 32];
            bhf[f] = *(const bf16x8*)&Bh[boff + f * 16 * 32];
            blf[f] = *(const bf16x8*)&Bl[boff + f * 16 * 32];
        }
#pragma unroll
        for (int i = 0; i < 4; i++)
#pragma unroll
            for (int j = 0; j < 4; j++) {
                acc[i][j] = __builtin_amdgcn_mfma_f32_16x16x32_bf16(
                    af[i], bhf[j], acc[i][j], 0, 0, 0);
                acc[i][j] = __builtin_amdgcn_mfma_f32_16x16x32_bf16(
                    af[i], blf[j], acc[i][j], 0, 0, 0);
            }
    }
    // C/D layout (m89-verified): col = lane&15, row = (lane>>4)*4 + reg
    int crow0 = mBase + wr * 64 + (lane >> 4) * 4;
    int ccol0 = nBase + wc * 64 + (lane & 15);
#pragma unroll
    for (int i = 0; i < 4; i++) {
#pragma unroll
        for (int j = 0; j < 4; j++) {
            int col = ccol0 + j * 16;
            float bv = bias[col];
#pragma unroll
            for (int r = 0; r < 4; r++) {
                int row = crow0 + i * 16 + r;
                C[(size_t)row * N + col] = acc[i][j][r] + bv;
            }
        }
    }
}

// ---------------- small f32 GEMM (split-K): P[z] = A @ B^T slice ------------
__global__ __launch_bounds__(256)
void k_gemm64(const float* __restrict__ A, const float* __restrict__ Bm,
              float* __restrict__ P, int M, int N, int K, int KS) {
    __shared__ float As[16][68];
    __shared__ float Bs[16][68];
    int tid = threadIdx.x;
    int mBase = blockIdx.y * 64, nBase = blockIdx.x * 64;
    int k0 = blockIdx.z * KS;
    int lr = tid >> 2, lk = (tid & 3) * 4;
    int ty = tid >> 4, tx = tid & 15;
    float acc[4][4];
#pragma unroll
    for (int i = 0; i < 4; i++)
#pragma unroll
        for (int j = 0; j < 4; j++) acc[i][j] = 0.0f;
    const float* Ap = A + (size_t)(mBase + lr) * K + k0 + lk;
    const float* Bp = Bm + (size_t)(nBase + lr) * K + k0 + lk;
    for (int k = 0; k < KS; k += 16) {
        float4 av = *(const float4*)(Ap + k);
        float4 bv = *(const float4*)(Bp + k);
        __syncthreads();
        As[lk + 0][lr] = av.x; As[lk + 1][lr] = av.y;
        As[lk + 2][lr] = av.z; As[lk + 3][lr] = av.w;
        Bs[lk + 0][lr] = bv.x; Bs[lk + 1][lr] = bv.y;
        Bs[lk + 2][lr] = bv.z; Bs[lk + 3][lr] = bv.w;
        __syncthreads();
#pragma unroll
        for (int kk = 0; kk < 16; ++kk) {
            float4 a4 = *(const float4*)&As[kk][ty * 4];
            float4 b4 = *(const float4*)&Bs[kk][tx * 4];
            float aa[4] = {a4.x, a4.y, a4.z, a4.w};
            float bb[4] = {b4.x, b4.y, b4.z, b4.w};
#pragma unroll
            for (int i = 0; i < 4; i++)
#pragma unroll
                for (int j = 0; j < 4; j++)
                    acc[i][j] = fmaf(aa[i], bb[j], acc[i][j]);
        }
    }
#pragma unroll
    for (int i = 0; i < 4; i++)
#pragma unroll
        for (int j = 0; j < 4; j++)
            P[((size_t)blockIdx.z * M + mBase + ty * 4 + i) * N + nBase + tx * 4 + j] =
                acc[i][j];
}

// ---------------- final reduce + epilogue ----------------
__global__ void k_fin(const float* __restrict__ P, const float* __restrict__ b2,
                      const float* __restrict__ scale, const float* __restrict__ bias2,
                      float* __restrict__ out, int M, int N, int Z) {
    int i = blockIdx.x * blockDim.x + threadIdx.x;
    if (i >= M * N) return;
    float s = 0.0f;
    for (int z = 0; z < Z; ++z) s += P[(size_t)z * M * N + i];
    int col = i % N;
    out[i] = (s + b2[col]) * scale[col] + bias2[col];
}

extern "C" void kernel_launch(void* const* d_in, const int* in_sizes, int n_in,
                              void* d_out, int out_size, void* d_ws, size_t ws_size,
                              hipStream_t stream) {
    const float* x = (const float*)d_in[0];
    const float* cd1 = (const float*)d_in[1];
    const float* v1 = (const float*)d_in[2];
    const float* cd2 = (const float*)d_in[3];
    const float* v2 = (const float*)d_in[4];
    const float* W1 = (const float*)d_in[5];
    const float* b1 = (const float*)d_in[6];
    const float* W2 = (const float*)d_in[7];
    const float* b2 = (const float*)d_in[8];
    const float* out_scale = (const float*)d_in[9];
    const float* out_bias = (const float*)d_in[10];

    int I = in_sizes[1];
    int H = in_sizes[3];
    int O = in_sizes[8];
    int Bsz = out_size / O;
    int T = in_sizes[0] / (Bsz * I);
    const int ZSPLIT = 4;

    float* ws = (float*)d_ws;
    size_t off = 0;
    auto alloc = [&](size_t n) {
        size_t cur = off;
        off += (n + 63) & ~(size_t)63;
        return cur;
    };
    size_t o_df1 = alloc(I);
    size_t o_df2 = alloc(H);
    size_t o_tw = alloc(T);
    size_t o_p1 = alloc((size_t)Bsz * I);
    size_t o_p2 = alloc((size_t)Bsz * H);
    size_t o_acc2 = alloc((size_t)Bsz * H);
    size_t o_whi = alloc((size_t)H * I / 2);   // ushort array in float units
    size_t o_wlo = alloc((size_t)H * I / 2);
    size_t o_part = alloc((size_t)ZSPLIT * Bsz * O);
    size_t persist = off;

    size_t wsFloats = ws_size / 4;
    size_t perStep = (size_t)Bsz * I / 2 + (size_t)Bsz * H + 128;
    int TC = 1;
    if (wsFloats > persist) {
        size_t tcMax = (wsFloats - persist) / perStep;
        TC = (int)(tcMax < (size_t)T ? tcMax : (size_t)T);
        if (TC < 1) TC = 1;
    }
    size_t o_s1 = alloc(((size_t)TC * Bsz * I + 1) / 2);
    size_t o_h = alloc((size_t)TC * Bsz * H);

    float* df1 = ws + o_df1;
    float* df2 = ws + o_df2;
    float* tw = ws + o_tw;
    float* p1 = ws + o_p1;
    float* p2 = ws + o_p2;
    float* acc2 = ws + o_acc2;
    ushort* whi = (ushort*)(ws + o_whi);
    ushort* wlo = (ushort*)(ws + o_wlo);
    float* part = ws + o_part;
    ushort* s1c = (ushort*)(ws + o_s1);
    float* hbuf = ws + o_h;

    k_init<<<2048, 256, 0, stream>>>(cd1, v1, cd2, v2, df1, df2, p1, p2, acc2, I, H,
                                     Bsz * I, Bsz * H);
    k_tw<<<1, 256, 0, stream>>>(v1, tw, T);
    k_wsplit<<<(H * I + 255) / 256, 256, 0, stream>>>(W1, whi, wlo, H * I);

    for (int t0 = 0; t0 < T; t0 += TC) {
        int tc = (T - t0 < TC) ? (T - t0) : TC;
        k_lif1<<<(Bsz * I + 255) / 256, 256, 0, stream>>>(x, df1, p1, s1c, Bsz, T, I,
                                                          t0, tc);
        int Mrows = tc * Bsz;                  // multiple of 128 (Bsz=256)
        int gx = H / 128;
        int nwg = (Mrows / 128) * gx;          // multiple of 32 → %8==0
        k_gemm_mfma<<<nwg, 256, 0, stream>>>(s1c, whi, wlo, b1, hbuf, H, I, gx);
        k_lif2<<<(Bsz * H + 255) / 256, 256, 0, stream>>>(hbuf, df2, tw, p2, acc2,
                                                          Bsz, H, t0, tc);
    }
    dim3 g2(O / 64, Bsz / 64, ZSPLIT);
    k_gemm64<<<g2, 256, 0, stream>>>(acc2, W2, part, Bsz, O, H, H / ZSPLIT);
    k_fin<<<(Bsz * O + 255) / 256, 256, 0, stream>>>(part, b2, out_scale, out_bias,
                                                     (float*)d_out, Bsz, O, ZSPLIT);
}

// Round 7
// 518.499 us; speedup vs baseline: 3.2229x; 1.0707x over previous
//
#include <hip/hip_runtime.h>
#include <hip/hip_bf16.h>
#include <math.h>

#define BETA_F 0.9f
#define THR1_F 1.0f
#define THR2_F 0.8f

typedef __attribute__((ext_vector_type(8))) short bf16x8;
typedef __attribute__((ext_vector_type(4))) float f32x4;

__device__ __forceinline__ void gload_lds16(const void* g, void* l) {
    __builtin_amdgcn_global_load_lds(
        (const __attribute__((address_space(1))) void*)g,
        (__attribute__((address_space(3))) void*)l, 16, 0, 0);
}

__device__ __forceinline__ ushort f2bf(float f) {
    __hip_bfloat16 h = __float2bfloat16(f);
    return *(ushort*)&h;
}
__device__ __forceinline__ float bf2f(ushort u) {
    __hip_bfloat16 h;
    *(ushort*)&h = u;
    return __bfloat162float(h);
}

// ---------------- init: delay factors + state zeroing ----------------
__global__ void k_init(const float* __restrict__ cd1, const float* __restrict__ v1,
                       const float* __restrict__ cd2, const float* __restrict__ v2,
                       float* __restrict__ df1, float* __restrict__ df2,
                       float* __restrict__ p1, float* __restrict__ p2,
                       float* __restrict__ acc2,
                       int I, int H, int BI, int BH) {
    float vc1 = fminf(fmaxf(v1[0], 0.0f), 0.999f);
    float vc2 = fminf(fmaxf(v2[0], 0.0f), 0.999f);
    double g1 = 1.0 / sqrt(1.0 - (double)vc1 * (double)vc1);
    double g2 = 1.0 / sqrt(1.0 - (double)vc2 * (double)vc2);
    int total = I + H + BI + BH + BH;
    for (int idx = blockIdx.x * blockDim.x + threadIdx.x; idx < total;
         idx += gridDim.x * blockDim.x) {
        if (idx < I) {
            df1[idx] = (float)exp(-(g1 * fabs((double)cd1[idx]) * (double)vc1));
        } else if (idx < I + H) {
            int j = idx - I;
            df2[j] = (float)exp(-(g2 * fabs((double)cd2[j]) * (double)vc2));
        } else if (idx < I + H + BI) {
            p1[idx - I - H] = 0.0f;
        } else if (idx < I + H + BI + BH) {
            p2[idx - I - H - BI] = 0.0f;
        } else {
            acc2[idx - I - H - BI - BH] = 0.0f;
        }
    }
}

// ---------------- time-weight table (normalized) ----------------
__global__ void k_tw(const float* __restrict__ v1, float* __restrict__ tw, int T) {
    __shared__ float sh[256];
    float vc = fminf(fmaxf(v1[0], 0.0f), 0.999f);
    double g = 1.0 / sqrt(1.0 - (double)vc * (double)vc);
    int t = threadIdx.x;
    float val = 0.0f;
    if (t < T) val = (float)exp(-(g - 1.0) * (double)t);
    sh[t] = val;
    __syncthreads();
    for (int s = 128; s > 0; s >>= 1) {
        if (t < s) sh[t] += sh[t + s];
        __syncthreads();
    }
    float sum = sh[0];
    if (t < T) tw[t] = val / sum;
}

// ---------------- split W1 into hi/lo bf16 ----------------
__global__ void k_wsplit(const float* __restrict__ W, ushort* __restrict__ hi,
                         ushort* __restrict__ lo, int n) {
    int i = blockIdx.x * blockDim.x + threadIdx.x;
    if (i >= n) return;
    float w = W[i];
    ushort h = f2bf(w);
    float hf = bf2f(h);
    ushort l = f2bf(w - hf);
    hi[i] = h;
    lo[i] = l;
}

// ---------------- layer-1 LIF over a chunk of timesteps (bf16 spikes) -------
__global__ void k_lif1(const float* __restrict__ x, const float* __restrict__ df1,
                       float* __restrict__ p1, ushort* __restrict__ s1,
                       int Bsz, int T, int I, int t0, int TC) {
    int idx = blockIdx.x * blockDim.x + threadIdx.x;  // b*I + i
    if (idx >= Bsz * I) return;
    int b = idx / I;
    int i = idx - b * I;
    float df = df1[i];
    float p = p1[idx];
    const float* xp = x + ((size_t)b * T + t0) * I + i;
    size_t strideS = (size_t)Bsz * I;
    for (int t = 0; t < TC; ++t) {
        float xv = xp[(size_t)t * I];
        float pn = __fadd_rn(__fmul_rn(p, BETA_F), __fmul_rn(xv, df));
        bool spk = pn > THR1_F;
        s1[(size_t)t * strideS + idx] = spk ? (ushort)0x3F80 : (ushort)0;
        p = spk ? 0.0f : pn;
    }
    p1[idx] = p;
}

// ---------------- layer-2 LIF + weighted spike accumulation ----------------
__global__ void k_lif2(const float* __restrict__ h, const float* __restrict__ df2,
                       const float* __restrict__ tw, float* __restrict__ p2,
                       float* __restrict__ acc2, int Bsz, int H, int t0, int TC) {
    int idx = blockIdx.x * blockDim.x + threadIdx.x;  // b*H + j
    if (idx >= Bsz * H) return;
    int j = idx % H;
    float df = df2[j];
    float p = p2[idx];
    float acc = acc2[idx];
    size_t strideH = (size_t)Bsz * H;
    for (int t = 0; t < TC; ++t) {
        float hv = h[(size_t)t * strideH + idx];
        float pn = __fadd_rn(__fmul_rn(p, BETA_F), __fmul_rn(hv, df));
        bool spk = pn > THR2_F;
        if (spk) acc += tw[t0 + t];
        p = spk ? 0.0f : pn;
    }
    p2[idx] = p;
    acc2[idx] = acc;
}

// ---------------- MFMA GEMM: C = A(bf16 spikes) @ (Whi+Wlo)^T + bias --------
// A: [M][K] bf16, Bhi/Blo: [N][K] bf16, C: [M][N] f32.
// BM=256, BN=128, BK=32, 512 threads (8 waves as 4Mx2N, wave tile 64x64).
// Double-buffered LDS + prefetch (T3-minimum 2-phase), XOR chunk swizzle (T2),
// setprio around MFMA clusters (T5), XCD-aware block swizzle (T1).
__global__ __launch_bounds__(512, 4)
void k_gemm_mfma(const ushort* __restrict__ A, const ushort* __restrict__ Bhi,
                 const ushort* __restrict__ Blo, const float* __restrict__ bias,
                 float* __restrict__ C, int N, int K, int gx) {
    __shared__ ushort As[2][8192];   // 256 rows x 32 (bf16)
    __shared__ ushort Bh[2][4096];   // 128 rows x 32
    __shared__ ushort Bl[2][4096];
    int nwg = gridDim.x;
    int lin = blockIdx.x;
    int cpx = nwg >> 3;                        // nwg % 8 == 0 by construction
    int swz = (lin & 7) * cpx + (lin >> 3);
    int bx = swz % gx, by = swz / gx;
    int mBase = by * 256, nBase = bx * 128;
    int tid = threadIdx.x;
    int wid = tid >> 6, lane = tid & 63;

    // ---- staging addresses: linear LDS dest, PRE-SWIZZLED global source ----
    // physical chunk slot = tid&3 holds global chunk (tid&3)^((row>>1)&3)
    int srow = tid >> 2;                       // 0..127
    int schunk = (tid & 3) ^ ((tid >> 3) & 3); // (tid&3) ^ ((srow>>1)&3)
    const ushort* aS0 = A + (size_t)(mBase + srow) * K + schunk * 8;
    const ushort* aS1 = A + (size_t)(mBase + 128 + srow) * K + schunk * 8;
    const ushort* bhS = Bhi + (size_t)(nBase + srow) * K + schunk * 8;
    const ushort* blS = Blo + (size_t)(nBase + srow) * K + schunk * 8;

    // ---- fragment read offsets (swizzled to match) ----
    int wr = wid >> 1, wc = wid & 1;           // wave tile: rows wr*64, cols wc*64
    int l15 = lane & 15;
    int sw = (l15 >> 1) & 3;                   // (row>>1)&3, uniform across f
    int ch = ((lane >> 4) ^ sw) * 8;
    int aoff = (wr * 64 + l15) * 32 + ch;
    int boff = (wc * 64 + l15) * 32 + ch;

    f32x4 acc[4][4];
#pragma unroll
    for (int i = 0; i < 4; i++)
#pragma unroll
        for (int j = 0; j < 4; j++) acc[i][j] = (f32x4)(0.0f);

    auto stage = [&](int buf, int k0) {
        gload_lds16(aS0 + k0, &As[buf][tid * 8]);
        gload_lds16(aS1 + k0, &As[buf][4096 + tid * 8]);
        gload_lds16(bhS + k0, &Bh[buf][tid * 8]);
        gload_lds16(blS + k0, &Bl[buf][tid * 8]);
    };
    auto compute_tile = [&](int cur) {
        bf16x8 af[4], bf[4];
#pragma unroll
        for (int f = 0; f < 4; f++) af[f] = *(const bf16x8*)&As[cur][aoff + f * 512];
#pragma unroll
        for (int f = 0; f < 4; f++) bf[f] = *(const bf16x8*)&Bh[cur][boff + f * 512];
        __builtin_amdgcn_s_setprio(1);
#pragma unroll
        for (int i = 0; i < 4; i++)
#pragma unroll
            for (int j = 0; j < 4; j++)
                acc[i][j] = __builtin_amdgcn_mfma_f32_16x16x32_bf16(af[i], bf[j],
                                                                    acc[i][j], 0, 0, 0);
        __builtin_amdgcn_s_setprio(0);
#pragma unroll
        for (int f = 0; f < 4; f++) bf[f] = *(const bf16x8*)&Bl[cur][boff + f * 512];
        __builtin_amdgcn_s_setprio(1);
#pragma unroll
        for (int i = 0; i < 4; i++)
#pragma unroll
            for (int j = 0; j < 4; j++)
                acc[i][j] = __builtin_amdgcn_mfma_f32_16x16x32_bf16(af[i], bf[j],
                                                                    acc[i][j], 0, 0, 0);
        __builtin_amdgcn_s_setprio(0);
    };

    int NT = K >> 5;
    stage(0, 0);
    __syncthreads();                            // compiler drains vmcnt(0) here
    for (int kt = 0; kt < NT - 1; ++kt) {
        stage((kt + 1) & 1, (kt + 1) << 5);     // prefetch next tile (in flight
        compute_tile(kt & 1);                   //  during this tile's MFMAs)
        __syncthreads();                        // vmcnt(0)+lgkmcnt(0) drain
    }
    compute_tile((NT - 1) & 1);

    // C/D layout (m89-verified): col = lane&15, row = (lane>>4)*4 + reg
    int crow0 = mBase + wr * 64 + (lane >> 4) * 4;
    int ccol0 = nBase + wc * 64 + l15;
#pragma unroll
    for (int i = 0; i < 4; i++) {
#pragma unroll
        for (int j = 0; j < 4; j++) {
            int col = ccol0 + j * 16;
            float bv = bias[col];
#pragma unroll
            for (int r = 0; r < 4; r++) {
                int row = crow0 + i * 16 + r;
                C[(size_t)row * N + col] = acc[i][j][r] + bv;
            }
        }
    }
}

// ---------------- small f32 GEMM (split-K): P[z] = A @ B^T slice ------------
__global__ __launch_bounds__(256)
void k_gemm64(const float* __restrict__ A, const float* __restrict__ Bm,
              float* __restrict__ P, int M, int N, int K, int KS) {
    __shared__ float As[16][68];
    __shared__ float Bs[16][68];
    int tid = threadIdx.x;
    int mBase = blockIdx.y * 64, nBase = blockIdx.x * 64;
    int k0 = blockIdx.z * KS;
    int lr = tid >> 2, lk = (tid & 3) * 4;
    int ty = tid >> 4, tx = tid & 15;
    float acc[4][4];
#pragma unroll
    for (int i = 0; i < 4; i++)
#pragma unroll
        for (int j = 0; j < 4; j++) acc[i][j] = 0.0f;
    const float* Ap = A + (size_t)(mBase + lr) * K + k0 + lk;
    const float* Bp = Bm + (size_t)(nBase + lr) * K + k0 + lk;
    for (int k = 0; k < KS; k += 16) {
        float4 av = *(const float4*)(Ap + k);
        float4 bv = *(const float4*)(Bp + k);
        __syncthreads();
        As[lk + 0][lr] = av.x; As[lk + 1][lr] = av.y;
        As[lk + 2][lr] = av.z; As[lk + 3][lr] = av.w;
        Bs[lk + 0][lr] = bv.x; Bs[lk + 1][lr] = bv.y;
        Bs[lk + 2][lr] = bv.z; Bs[lk + 3][lr] = bv.w;
        __syncthreads();
#pragma unroll
        for (int kk = 0; kk < 16; ++kk) {
            float4 a4 = *(const float4*)&As[kk][ty * 4];
            float4 b4 = *(const float4*)&Bs[kk][tx * 4];
            float aa[4] = {a4.x, a4.y, a4.z, a4.w};
            float bb[4] = {b4.x, b4.y, b4.z, b4.w};
#pragma unroll
            for (int i = 0; i < 4; i++)
#pragma unroll
                for (int j = 0; j < 4; j++)
                    acc[i][j] = fmaf(aa[i], bb[j], acc[i][j]);
        }
    }
#pragma unroll
    for (int i = 0; i < 4; i++)
#pragma unroll
        for (int j = 0; j < 4; j++)
            P[((size_t)blockIdx.z * M + mBase + ty * 4 + i) * N + nBase + tx * 4 + j] =
                acc[i][j];
}

// ---------------- final reduce + epilogue ----------------
__global__ void k_fin(const float* __restrict__ P, const float* __restrict__ b2,
                      const float* __restrict__ scale, const float* __restrict__ bias2,
                      float* __restrict__ out, int M, int N, int Z) {
    int i = blockIdx.x * blockDim.x + threadIdx.x;
    if (i >= M * N) return;
    float s = 0.0f;
    for (int z = 0; z < Z; ++z) s += P[(size_t)z * M * N + i];
    int col = i % N;
    out[i] = (s + b2[col]) * scale[col] + bias2[col];
}

extern "C" void kernel_launch(void* const* d_in, const int* in_sizes, int n_in,
                              void* d_out, int out_size, void* d_ws, size_t ws_size,
                              hipStream_t stream) {
    const float* x = (const float*)d_in[0];
    const float* cd1 = (const float*)d_in[1];
    const float* v1 = (const float*)d_in[2];
    const float* cd2 = (const float*)d_in[3];
    const float* v2 = (const float*)d_in[4];
    const float* W1 = (const float*)d_in[5];
    const float* b1 = (const float*)d_in[6];
    const float* W2 = (const float*)d_in[7];
    const float* b2 = (const float*)d_in[8];
    const float* out_scale = (const float*)d_in[9];
    const float* out_bias = (const float*)d_in[10];

    int I = in_sizes[1];
    int H = in_sizes[3];
    int O = in_sizes[8];
    int Bsz = out_size / O;
    int T = in_sizes[0] / (Bsz * I);
    const int ZSPLIT = 4;

    float* ws = (float*)d_ws;
    size_t off = 0;
    auto alloc = [&](size_t n) {
        size_t cur = off;
        off += (n + 63) & ~(size_t)63;
        return cur;
    };
    size_t o_df1 = alloc(I);
    size_t o_df2 = alloc(H);
    size_t o_tw = alloc(T);
    size_t o_p1 = alloc((size_t)Bsz * I);
    size_t o_p2 = alloc((size_t)Bsz * H);
    size_t o_acc2 = alloc((size_t)Bsz * H);
    size_t o_whi = alloc((size_t)H * I / 2);   // ushort array in float units
    size_t o_wlo = alloc((size_t)H * I / 2);
    size_t o_part = alloc((size_t)ZSPLIT * Bsz * O);
    size_t persist = off;

    size_t wsFloats = ws_size / 4;
    size_t perStep = (size_t)Bsz * I / 2 + (size_t)Bsz * H + 128;
    int TC = 1;
    if (wsFloats > persist) {
        size_t tcMax = (wsFloats - persist) / perStep;
        TC = (int)(tcMax < (size_t)T ? tcMax : (size_t)T);
        if (TC < 1) TC = 1;
    }
    size_t o_s1 = alloc(((size_t)TC * Bsz * I + 1) / 2);
    size_t o_h = alloc((size_t)TC * Bsz * H);

    float* df1 = ws + o_df1;
    float* df2 = ws + o_df2;
    float* tw = ws + o_tw;
    float* p1 = ws + o_p1;
    float* p2 = ws + o_p2;
    float* acc2 = ws + o_acc2;
    ushort* whi = (ushort*)(ws + o_whi);
    ushort* wlo = (ushort*)(ws + o_wlo);
    float* part = ws + o_part;
    ushort* s1c = (ushort*)(ws + o_s1);
    float* hbuf = ws + o_h;

    k_init<<<2048, 256, 0, stream>>>(cd1, v1, cd2, v2, df1, df2, p1, p2, acc2, I, H,
                                     Bsz * I, Bsz * H);
    k_tw<<<1, 256, 0, stream>>>(v1, tw, T);
    k_wsplit<<<(H * I + 255) / 256, 256, 0, stream>>>(W1, whi, wlo, H * I);

    for (int t0 = 0; t0 < T; t0 += TC) {
        int tc = (T - t0 < TC) ? (T - t0) : TC;
        k_lif1<<<(Bsz * I + 255) / 256, 256, 0, stream>>>(x, df1, p1, s1c, Bsz, T, I,
                                                          t0, tc);
        int Mrows = tc * Bsz;                  // tc*256 → multiple of 256
        int gx = H / 128;
        int nwg = (Mrows / 256) * gx;          // tc*16 → always %8==0
        k_gemm_mfma<<<nwg, 512, 0, stream>>>(s1c, whi, wlo, b1, hbuf, H, I, gx);
        k_lif2<<<(Bsz * H + 255) / 256, 256, 0, stream>>>(hbuf, df2, tw, p2, acc2,
                                                          Bsz, H, t0, tc);
    }
    dim3 g2(O / 64, Bsz / 64, ZSPLIT);
    k_gemm64<<<g2, 256, 0, stream>>>(acc2, W2, part, Bsz, O, H, H / ZSPLIT);
    k_fin<<<(Bsz * O + 255) / 256, 256, 0, stream>>>(part, b2, out_scale, out_bias,
                                                     (float*)d_out, Bsz, O, ZSPLIT);
}